// Round 6
// baseline (22.062 us; speedup 1.0000x reference)
//
#include <hip/hip_runtime.h>
#include <hip/hip_bf16.h>

#define HW 128

typedef __attribute__((ext_vector_type(8))) short bf16x8;
typedef __attribute__((ext_vector_type(4))) float f32x4;

__device__ __forceinline__ ushort f2bf(float x) {
  uint u = __builtin_bit_cast(uint, x);
  u += 0x7FFFu + ((u >> 16) & 1u);   // RNE; inputs finite
  return (ushort)(u >> 16);
}

// B layout: Wb[((t*16 + i)*4 + lq)*8 + e]  (bf16), t = n*5+q (45 chunks of 1KB)
// k = q*32 + lq*8 + e in [0,160): j = k/10, c = k%10
// value: c==0 -> sum_m base_w; c in 1..8 -> sum_m spline_w[c-1]*scaler; c==9 -> 0
__global__ void kan_prep(const float* __restrict__ bw, const float* __restrict__ sw,
                         const float* __restrict__ sc, ushort* __restrict__ Wb) {
  int idx = blockIdx.x * 256 + threadIdx.x;
  if (idx >= 45 * 512) return;
  int e  = idx & 7;
  int lq = (idx >> 3) & 3;
  int i  = (idx >> 5) & 15;
  int t  = idx >> 9;
  int n = t / 5, q = t % 5;
  int k = q * 32 + lq * 8 + e;
  int j = k / 10, c = k % 10;
  float s = 0.f;
  if (c == 0) {
#pragma unroll
    for (int m = 0; m < 9; ++m) s += bw[((i * 16 + j) * 9 + m) * 9 + n];
  } else if (c <= 8) {
#pragma unroll
    for (int m = 0; m < 9; ++m) {
      int base = ((i * 16 + j) * 9 + m) * 9 + n;
      s += sw[base * 8 + (c - 1)] * sc[base];
    }
  }
  Wb[idx] = f2bf(s);
}

#define PSTRIDE 336                 // 160 bf16 (k=j*10+c) + 16B pad; bank-uniform A-reads
#define HALO_PX 180                 // 10 rows x 18 cols

// Closed-form uniform cubic B-spline features: silu + 4 nonzero bases scattered.
// blk: 20B block for (pixel, channel); dump: pixel pad bytes (never read).
__device__ __forceinline__ void kan_feat_store(char* __restrict__ blk,
                                               char* __restrict__ dump, float x) {
  float sil = __fdividef(x, 1.0f + __expf(-x));
  float t = (x + 2.2f) * 2.5f;
  float fi = floorf(t);
  float u = t - fi;
  int i = (int)fi;
  float u2 = u * u, u3 = u2 * u;
  float v = 1.0f - u;
  float B0 = v * v * v * (1.0f / 6.0f);
  float B1 = fmaf(0.5f, u3, (2.0f / 3.0f) - u2);
  float B2 = fmaf(0.5f, (u + u2) - u3, 1.0f / 6.0f);
  float B3 = u3 * (1.0f / 6.0f);

  uint* w = (uint*)blk;
  w[0] = (uint)f2bf(sil);   // (silu, 0)
  w[1] = 0; w[2] = 0; w[3] = 0; w[4] = 0;

  // nonzero bases at s = i-3+d, d=0..3; valid iff (uint)s < 8 (covers range check)
  char* pa = blk + 2 * i - 4;   // = blk + 2*(1 + (i-3))
#pragma unroll
  for (int d = 0; d < 4; ++d) {
    float B = (d == 0) ? B0 : (d == 1) ? B1 : (d == 2) ? B2 : B3;
    bool ok = (unsigned)(i - 3 + d) < 8u;
    char* addr = ok ? (pa + 2 * d) : dump;
    *(ushort*)addr = f2bf(B);
  }
}

__global__ __launch_bounds__(256, 2) void kan_mfma(
    const float* __restrict__ X, const ushort* __restrict__ Wb,
    const float* __restrict__ bias, float* __restrict__ out) {
  __shared__ char smem[HALO_PX * PSTRIDE];   // 60480 B

  int tid = threadIdx.x;
  int lane = tid & 63;
  int wid = tid >> 6;                 // 4 waves; wave owns output rows wid, wid+4
  int bid = blockIdx.x;
  int b = bid >> 7;
  int tile = bid & 127;
  int h0 = (tile >> 3) << 3;          // 16 row-tiles of 8
  int w0 = (tile & 7) << 4;           // 8 col-tiles of 16
  int li = lane & 15;
  int lq = lane >> 4;

  const char* wbase = (const char*)Wb + li * 64 + lq * 16;

  // Single-buffered B-frags: 15 chunks = 60 VGPRs (fits the 128-VGPR cap, no spill).
  // Sub-pass 0 issued before features: L2 latency hides under feature phase.
  bf16x8 Bbuf[15];
#pragma unroll
  for (int t = 0; t < 15; ++t)
    Bbuf[t] = *(const bf16x8*)(wbase + t * 1024);

  // ---- feature phase: 720 quad-tasks (180 px x 4 channel-quads) ----
#pragma unroll
  for (int r = 0; r < 3; ++r) {
    int tq = r * 256 + tid;
    if (tq < 720) {
      int p = tq >> 2, jq = tq & 3;
      int hh = p / 18, ww = p - hh * 18;
      int gh = h0 + hh - 1, gw = w0 + ww - 1;
      bool inb = (gh >= 0) & (gh < HW) & (gw >= 0) & (gw < HW);
      const float* xp = X + ((b * 16 + jq * 4) << 14) + (gh << 7) + gw;
      char* pix = smem + p * PSTRIDE;
      char* blk = pix + jq * 80;
      char* dump = pix + 326;
#pragma unroll
      for (int jl = 0; jl < 4; ++jl) {
        float xv = inb ? xp[jl << 14] : 0.f;  // pad pixel: x=0, features still stored
        kan_feat_store(blk + jl * 20, dump, xv);
      }
    }
  }
  __syncthreads();

  // ---- MFMA phase: 3 sub-passes x (5 chunks x 3 taps) x 2 rows ----
  // Bbuf[tt] is reloaded with next sub-pass's chunk right after its last use:
  // write-after-read issues immediately, ~14 MFMA-pairs of latency cover.
  f32x4 acc0 = {0.f, 0.f, 0.f, 0.f};
  f32x4 acc1 = {0.f, 0.f, 0.f, 0.f};
  int ab = li * PSTRIDE + lq * 16;
  const char* base0 = smem + wid * (18 * PSTRIDE) + ab;          // row wid
  const char* base1 = smem + (wid + 4) * (18 * PSTRIDE) + ab;    // row wid+4

#pragma unroll
  for (int s = 0; s < 3; ++s) {
#pragma unroll
    for (int tt = 0; tt < 15; ++tt) {
      const int t = s * 15 + tt;
      const int n = t / 5, q = t - n * 5;
      const int dh = n / 3, dw = n - dh * 3;
      const int imm = (dh * 18 + dw) * PSTRIDE + q * 64;
      bf16x8 a0 = *(const bf16x8*)(base0 + imm);
      acc0 = __builtin_amdgcn_mfma_f32_16x16x32_bf16(a0, Bbuf[tt], acc0, 0, 0, 0);
      bf16x8 a1 = *(const bf16x8*)(base1 + imm);
      acc1 = __builtin_amdgcn_mfma_f32_16x16x32_bf16(a1, Bbuf[tt], acc1, 0, 0, 0);
      if (s < 2)
        Bbuf[tt] = *(const bf16x8*)(wbase + ((s + 1) * 15 + tt) * 1024);
    }
  }

  // ---- epilogue: lane holds i=li, pixels w = lq*4 + reg, rows wid / wid+4 ----
  float bias_v = bias[li];
  float* op0 = out + ((b * 16 + li) << 14) + ((h0 + wid) << 7) + w0 + lq * 4;
  float* op1 = out + ((b * 16 + li) << 14) + ((h0 + wid + 4) << 7) + w0 + lq * 4;
  float4 v0, v1;
  v0.x = acc0[0] + bias_v; v0.y = acc0[1] + bias_v;
  v0.z = acc0[2] + bias_v; v0.w = acc0[3] + bias_v;
  v1.x = acc1[0] + bias_v; v1.y = acc1[1] + bias_v;
  v1.z = acc1[2] + bias_v; v1.w = acc1[3] + bias_v;
  *reinterpret_cast<float4*>(op0) = v0;
  *reinterpret_cast<float4*>(op1) = v1;
}

extern "C" void kernel_launch(void* const* d_in, const int* in_sizes, int n_in,
                              void* d_out, int out_size, void* d_ws, size_t ws_size,
                              hipStream_t stream) {
  const float* x    = (const float*)d_in[0];
  const float* bw   = (const float*)d_in[1];
  const float* sw   = (const float*)d_in[2];
  const float* sc   = (const float*)d_in[3];
  const float* bias = (const float*)d_in[4];
  float* out = (float*)d_out;
  ushort* Wb = (ushort*)d_ws;   // 45*512 bf16 = 46080 B

  hipLaunchKernelGGL(kan_prep, dim3(90), dim3(256), 0, stream, bw, sw, sc, Wb);
  hipLaunchKernelGGL(kan_mfma, dim3(512), dim3(256), 0, stream, x, Wb, bias, out);
}